// Round 5
// baseline (2804.760 us; speedup 1.0000x reference)
//
#include <hip/hip_runtime.h>
#include <cstdint>
#include <cstddef>

#define BB 8
#define NN 4096
#define FF 64
#define SS 2048
#define KK 64
#define H1c 64
#define H2c 64
#define H3c 128
#define R2 0.04f
#define CAP 448

typedef unsigned long long ull;

// Exact (numpy-order, non-fma) squared distance: (dx*dx + dy*dy) + dz*dz
__device__ __forceinline__ float d2_exact(float ax, float ay, float az,
                                          float bx, float by, float bz) {
  float dx = __fsub_rn(ax, bx);
  float dy = __fsub_rn(ay, by);
  float dz = __fsub_rn(az, bz);
  return __fadd_rn(__fadd_rn(__fmul_rn(dx, dx), __fmul_rn(dy, dy)), __fmul_rn(dz, dz));
}

__device__ __forceinline__ int part3(int v) {
  return (v & 1) | ((v & 2) << 2) | ((v & 4) << 4);
}

// wave-64 max via DPP; result valid in lane 63. Identity 0 ok for our uses
// (f32 bit patterns of non-negative floats, or unsigned ~idx payloads).
#define WAVE_MAX_DPP(v)                                                        \
  do {                                                                         \
    v = max(v, __builtin_amdgcn_update_dpp(0, v, 0x111, 0xf, 0xf, true));      \
    v = max(v, __builtin_amdgcn_update_dpp(0, v, 0x112, 0xf, 0xf, true));      \
    v = max(v, __builtin_amdgcn_update_dpp(0, v, 0x114, 0xf, 0xf, true));      \
    v = max(v, __builtin_amdgcn_update_dpp(0, v, 0x118, 0xf, 0xf, true));      \
    v = max(v, __builtin_amdgcn_update_dpp(0, v, 0x142, 0xf, 0xf, true));      \
    v = max(v, __builtin_amdgcn_update_dpp(0, v, 0x143, 0xf, 0xf, true));      \
  } while (0)

// ---------------- Kernel 1: farthest point sampling with spatial pruning ----
// One block (256 threads) per cloud. One-time: Morton-cell counting sort so
// each thread owns 16 spatially-local points (original indices kept in jj[]
// -> argmax key semantics identical to numpy regardless of storage order).
// Per step: conservative gate test (skip exact update when the chunk provably
// can't change); exact d2+u64-key tree only when gated in; per-wave cached
// key + DPP value reduce only when some lane updated; single barrier.
__global__ __launch_bounds__(256) void fps_kernel(const float* __restrict__ pos,
                                                  float* __restrict__ pos_out,
                                                  float* __restrict__ batch_out) {
  __shared__ float plds[NN * 3];       // 48 KB, coords by ORIGINAL index
  __shared__ int sortIdx[NN];          // 16 KB
  __shared__ int ccnt[512], coff[512], ccur[512];
  __shared__ ull skey[2][4];
  const int b = blockIdx.x;
  const int tid = threadIdx.x;
  const int lane = tid & 63, wv = tid >> 6;

  const float4* src = (const float4*)(pos + (size_t)b * NN * 3);
  float4* dstl = (float4*)plds;
#pragma unroll
  for (int k = 0; k < 12; ++k) dstl[tid + k * 256] = src[tid + k * 256];
  ccnt[tid] = 0;
  ccnt[tid + 256] = 0;
  __syncthreads();

  // count
  for (int i = 0; i < 16; ++i) {
    int j = tid * 16 + i;
    int ix = min(7, (int)(plds[j * 3 + 0] * 8.0f));
    int iy = min(7, (int)(plds[j * 3 + 1] * 8.0f));
    int iz = min(7, (int)(plds[j * 3 + 2] * 8.0f));
    int c = part3(ix) | (part3(iy) << 1) | (part3(iz) << 2);
    atomicAdd(&ccnt[c], 1);
  }
  __syncthreads();
  coff[tid] = ccnt[tid];
  coff[tid + 256] = ccnt[tid + 256];
  // Blelloch exclusive scan over 512
  for (int d = 1; d < 512; d <<= 1) {
    __syncthreads();
    int i = (tid + 1) * (d << 1) - 1;
    if (i < 512) coff[i] += coff[i - d];
  }
  __syncthreads();
  if (tid == 0) coff[511] = 0;
  for (int d = 256; d >= 1; d >>= 1) {
    __syncthreads();
    int i = (tid + 1) * (d << 1) - 1;
    if (i < 512) {
      int t = coff[i - d];
      coff[i - d] = coff[i];
      coff[i] += t;
    }
  }
  __syncthreads();
  ccur[tid] = coff[tid];
  ccur[tid + 256] = coff[tid + 256];
  __syncthreads();
  // scatter (intra-cell order nondeterministic -> harmless: keys carry idx)
  for (int i = 0; i < 16; ++i) {
    int j = tid * 16 + i;
    int ix = min(7, (int)(plds[j * 3 + 0] * 8.0f));
    int iy = min(7, (int)(plds[j * 3 + 1] * 8.0f));
    int iz = min(7, (int)(plds[j * 3 + 2] * 8.0f));
    int c = part3(ix) | (part3(iy) << 1) | (part3(iz) << 2);
    int slot = atomicAdd(&ccur[c], 1);
    sortIdx[slot] = j;
  }
  __syncthreads();

  // private chunk: 16 spatially-local points
  float px[16], py[16], pz[16], dmin[16];
  int jj[16];
  float bxmin = 1e9f, bxmax = -1e9f, bymin = 1e9f, bymax = -1e9f, bzmin = 1e9f,
        bzmax = -1e9f;
#pragma unroll
  for (int i = 0; i < 16; ++i) {
    int j = sortIdx[tid * 16 + i];
    jj[i] = j;
    px[i] = plds[j * 3 + 0];
    py[i] = plds[j * 3 + 1];
    pz[i] = plds[j * 3 + 2];
    dmin[i] = INFINITY;
    bxmin = fminf(bxmin, px[i]); bxmax = fmaxf(bxmax, px[i]);
    bymin = fminf(bymin, py[i]); bymax = fmaxf(bymax, py[i]);
    bzmin = fminf(bzmin, pz[i]); bzmax = fmaxf(bzmax, pz[i]);
  }
  const float qx = 0.5f * (bxmin + bxmax);
  const float qy = 0.5f * (bymin + bymax);
  const float qz = 0.5f * (bzmin + bzmax);
  float r2m = 0.f;
#pragma unroll
  for (int i = 0; i < 16; ++i) {
    float dx = px[i] - qx, dy = py[i] - qy, dz = pz[i] - qz;
    r2m = fmaxf(r2m, dx * dx + dy * dy + dz * dz);
  }
  const float rchunk = sqrtf(r2m) * 1.00001f + 1e-5f;  // conservative radius

  float gate = INFINITY;  // (rchunk + sqrt(m))^2, inf -> always update
  ull mykey = 0, wkey_reg = 0;
  float cx = plds[0], cy = plds[1], cz = plds[2];

  for (int s = 0; s < SS; ++s) {
    if (tid == 0) {
      int o = b * SS + s;
      pos_out[o * 3 + 0] = cx;
      pos_out[o * 3 + 1] = cy;
      pos_out[o * 3 + 2] = cz;
      batch_out[o] = (float)b;
    }
    // gate: can this chunk's dmin change?
    const float gdx = qx - cx, gdy = qy - cy, gdz = qz - cz;
    const float d2q = gdx * gdx + gdy * gdy + gdz * gdz;
    const bool upd = (d2q < gate);
    if (upd) {
      ull kk[16];
#pragma unroll
      for (int i = 0; i < 16; ++i) {
        float d = d2_exact(px[i], py[i], pz[i], cx, cy, cz);
        dmin[i] = fminf(dmin[i], d);
        kk[i] = ((ull)__float_as_uint(dmin[i]) << 32) | (unsigned)(~jj[i]);
      }
#pragma unroll
      for (int st = 1; st < 16; st <<= 1)
#pragma unroll
        for (int i = 0; i < 16; i += 2 * st)
          if (kk[i + st] > kk[i]) kk[i] = kk[i + st];
      mykey = kk[0];
      const float m = __uint_as_float((unsigned)(mykey >> 32));
      const float rg = rchunk + (sqrtf(m) * 1.00001f + 1e-5f);
      gate = rg * rg;
    }
    // per-wave reduce only if some lane changed (keys are otherwise stale)
    if (__any(upd)) {
      const int hi = (int)(unsigned)(mykey >> 32);
      int v = hi;
      WAVE_MAX_DPP(v);
      const int wmax = __builtin_amdgcn_readlane(v, 63);
      const ull bal = __ballot(hi == wmax);
      unsigned klo;
      if (__popcll(bal) == 1) {
        const int wl = (int)__builtin_ctzll(bal);
        klo = (unsigned)__builtin_amdgcn_readlane((int)(unsigned)mykey, wl);
      } else {
        // exact tie on value (rare): unsigned-max of ~idx among tied lanes
        // (~idx has top bits 1 for idx<2^31 ... but as unsigned max over
        //  payloads, larger ~idx == smaller idx, exactly numpy's tie-break)
        int l = (hi == wmax) ? (int)(unsigned)mykey : 0;
        unsigned ul = (unsigned)l;
        // unsigned max via signed max trick not safe; do it with umax ops:
        unsigned t;
        t = (unsigned)__builtin_amdgcn_update_dpp(0, (int)ul, 0x111, 0xf, 0xf, true);
        ul = ul > t ? ul : t;
        t = (unsigned)__builtin_amdgcn_update_dpp(0, (int)ul, 0x112, 0xf, 0xf, true);
        ul = ul > t ? ul : t;
        t = (unsigned)__builtin_amdgcn_update_dpp(0, (int)ul, 0x114, 0xf, 0xf, true);
        ul = ul > t ? ul : t;
        t = (unsigned)__builtin_amdgcn_update_dpp(0, (int)ul, 0x118, 0xf, 0xf, true);
        ul = ul > t ? ul : t;
        t = (unsigned)__builtin_amdgcn_update_dpp(0, (int)ul, 0x142, 0xf, 0xf, true);
        ul = ul > t ? ul : t;
        t = (unsigned)__builtin_amdgcn_update_dpp(0, (int)ul, 0x143, 0xf, 0xf, true);
        ul = ul > t ? ul : t;
        klo = (unsigned)__builtin_amdgcn_readlane((int)ul, 63);
      }
      wkey_reg = ((ull)(unsigned)wmax << 32) | klo;
    }
    const int buf = s & 1;
    if (lane == 0) skey[buf][wv] = wkey_reg;
    __syncthreads();

    const ull k0 = skey[buf][0], k1 = skey[buf][1];
    const ull k2 = skey[buf][2], k3 = skey[buf][3];
    ull ka = k0 > k1 ? k0 : k1;
    const ull kb2 = k2 > k3 ? k2 : k3;
    if (kb2 > ka) ka = kb2;
    const int cur = (int)(~(unsigned)(ka & 0xffffffffu));
    cx = plds[cur * 3 + 0];
    cy = plds[cur * 3 + 1];
    cz = plds[cur * 3 + 2];
  }
}

// ---------------- Kernel 2: y1 = x @ W1[0:64,:] + b1 (no relu) ---------------
__global__ __launch_bounds__(256) void y1_kernel(const float* __restrict__ x,
                                                 const float* __restrict__ W1,
                                                 const float* __restrict__ b1,
                                                 float* __restrict__ y1) {
  __shared__ float xs[64][65];
  const int tid = threadIdx.x;
  const int r0 = blockIdx.x * 64;
  const float4* src = (const float4*)(x + (size_t)r0 * FF);
#pragma unroll
  for (int q = 0; q < 4; q++) {
    int p = tid + q * 256;
    float4 v = src[p];
    int row = (p * 4) >> 6, col = (p * 4) & 63;
    xs[row][col + 0] = v.x;
    xs[row][col + 1] = v.y;
    xs[row][col + 2] = v.z;
    xs[row][col + 3] = v.w;
  }
  __syncthreads();
  const int c4 = (tid & 15) * 4, kb = (tid >> 4) * 4;
  float acc[4][4];
#pragma unroll
  for (int kk = 0; kk < 4; kk++) {
    acc[kk][0] = b1[c4 + 0];
    acc[kk][1] = b1[c4 + 1];
    acc[kk][2] = b1[c4 + 2];
    acc[kk][3] = b1[c4 + 3];
  }
  for (int f = 0; f < FF; ++f) {
    float4 w = *(const float4*)(W1 + f * H1c + c4);
#pragma unroll
    for (int kk = 0; kk < 4; kk++) {
      float a = xs[kb + kk][f];
      acc[kk][0] += a * w.x;
      acc[kk][1] += a * w.y;
      acc[kk][2] += a * w.z;
      acc[kk][3] += a * w.w;
    }
  }
#pragma unroll
  for (int kk = 0; kk < 4; kk++) {
    float4 o;
    o.x = acc[kk][0]; o.y = acc[kk][1]; o.z = acc[kk][2]; o.w = acc[kk][3];
    *(float4*)(y1 + (size_t)(r0 + kb + kk) * H1c + c4) = o;
  }
}

// ---------------- Kernel 3: radius ball query, K nearest inside R -----------
__global__ __launch_bounds__(256) void ballq_kernel(const float* __restrict__ pos,
                                                    const float* __restrict__ pos_out,
                                                    int* __restrict__ nbr) {
  __shared__ float plds[NN * 3];
  __shared__ float d2c[4][CAP];
  __shared__ int idxc[4][CAP];
  const int tid = threadIdx.x;
  const int b = blockIdx.x >> 6;
  const int chunk = blockIdx.x & 63;
  const float4* src = (const float4*)(pos + (size_t)b * NN * 3);
  float4* dstl = (float4*)plds;
#pragma unroll
  for (int k = 0; k < 12; k++) dstl[tid + k * 256] = src[tid + k * 256];
  __syncthreads();

  const int w = tid >> 6, lane = tid & 63;
  for (int t8 = 0; t8 < 8; ++t8) {
    const int s = chunk * 32 + w * 8 + t8;
    const int g = b * SS + s;
    const float cx = pos_out[g * 3 + 0], cy = pos_out[g * 3 + 1], cz = pos_out[g * 3 + 2];
    int cnt = 0;
    for (int t = 0; t < 64; ++t) {
      int j = t * 64 + lane;
      float d2 = d2_exact(plds[j * 3 + 0], plds[j * 3 + 1], plds[j * 3 + 2], cx, cy, cz);
      bool pred = (d2 <= R2);
      unsigned long long mask = __ballot(pred);
      if (pred) {
        int p = cnt + __popcll(mask & ((1ull << lane) - 1ull));
        if (p < CAP) { d2c[w][p] = d2; idxc[w][p] = j; }
      }
      cnt += (int)__popcll(mask);
    }
    int M = cnt < CAP ? cnt : CAP;
    __syncthreads();  // make this wave's LDS list visible to itself safely

    if (M <= 64) {
      int v = (lane < M) ? (b * NN + idxc[w][lane]) : -1;
      nbr[(size_t)g * KK + lane] = v;
    } else {
      float ed[7];
      int ei[7];
#pragma unroll
      for (int q = 0; q < 7; q++) {
        int p = lane + q * 64;
        if (p < M) { ed[q] = d2c[w][p]; ei[q] = idxc[w][p]; }
        else { ed[q] = 0.f; ei[q] = -1; }
      }
      for (int it = 0; it < KK; ++it) {
        unsigned long long key = ~0ull;
#pragma unroll
        for (int q = 0; q < 7; q++) {
          if (ei[q] >= 0) {
            unsigned long long k2 =
                ((unsigned long long)__float_as_uint(ed[q]) << 32) | (unsigned)ei[q];
            if (k2 < key) key = k2;
          }
        }
#pragma unroll
        for (int off = 32; off; off >>= 1) {
          unsigned long long ok = __shfl_xor(key, off);
          if (ok < key) key = ok;
        }
        int widx = (int)(key & 0xffffffffull);
        if (lane == it) nbr[(size_t)g * KK + it] = b * NN + widx;
#pragma unroll
        for (int q = 0; q < 7; q++) {
          if (ei[q] == widx) ei[q] = -1;
        }
      }
    }
    __syncthreads();  // lists reused next iteration
  }
}

// ---------------- Kernel 4: per-centroid MLP (layers 1-3) + max aggregation -
__global__ __launch_bounds__(256) void mlp_kernel(const float* __restrict__ pos,
                                                  const float* __restrict__ y1,
                                                  const float* __restrict__ W1,
                                                  const float* __restrict__ W2,
                                                  const float* __restrict__ b2,
                                                  const float* __restrict__ W3,
                                                  const float* __restrict__ b3,
                                                  const int* __restrict__ nbr,
                                                  const float* __restrict__ pos_out,
                                                  float* __restrict__ x_out) {
  __shared__ float h1[64][65];
  __shared__ float h2[64][65];
  __shared__ int nl[64];
  const int g = blockIdx.x;
  const int tid = threadIdx.x;
  if (tid < 64) nl[tid] = nbr[(size_t)g * KK + tid];
  const float cx = pos_out[g * 3 + 0], cy = pos_out[g * 3 + 1], cz = pos_out[g * 3 + 2];
  __syncthreads();
  {
    const int k = tid >> 2, h0 = (tid & 3) * 16;
    const int j = nl[k];
    if (j >= 0) {
      const float* yr = y1 + (size_t)j * H1c;
      const float rx = pos[j * 3 + 0] - cx;
      const float ry = pos[j * 3 + 1] - cy;
      const float rz = pos[j * 3 + 2] - cz;
#pragma unroll
      for (int h = 0; h < 16; ++h) {
        int hh = h0 + h;
        float v = yr[hh] + rx * W1[64 * H1c + hh] + ry * W1[65 * H1c + hh] +
                  rz * W1[66 * H1c + hh];
        h1[k][hh] = fmaxf(v, 0.f);
      }
    } else {
#pragma unroll
      for (int h = 0; h < 16; ++h) h1[k][h0 + h] = 0.f;
    }
  }
  __syncthreads();
  {
    const int c4 = (tid & 15) * 4, kb = (tid >> 4) * 4;
    float acc[4][4];
#pragma unroll
    for (int kk = 0; kk < 4; kk++) {
      acc[kk][0] = b2[c4 + 0];
      acc[kk][1] = b2[c4 + 1];
      acc[kk][2] = b2[c4 + 2];
      acc[kk][3] = b2[c4 + 3];
    }
    for (int f = 0; f < H1c; ++f) {
      float4 wv = *(const float4*)(W2 + f * H2c + c4);
#pragma unroll
      for (int kk = 0; kk < 4; kk++) {
        float a = h1[kb + kk][f];
        acc[kk][0] += a * wv.x;
        acc[kk][1] += a * wv.y;
        acc[kk][2] += a * wv.z;
        acc[kk][3] += a * wv.w;
      }
    }
#pragma unroll
    for (int kk = 0; kk < 4; kk++) {
      h2[kb + kk][c4 + 0] = fmaxf(acc[kk][0], 0.f);
      h2[kb + kk][c4 + 1] = fmaxf(acc[kk][1], 0.f);
      h2[kb + kk][c4 + 2] = fmaxf(acc[kk][2], 0.f);
      h2[kb + kk][c4 + 3] = fmaxf(acc[kk][3], 0.f);
    }
  }
  __syncthreads();
  {
    const int c4 = (tid & 31) * 4, kb = (tid >> 5) * 8;
    float acc[8][4];
#pragma unroll
    for (int kk = 0; kk < 8; kk++) {
      acc[kk][0] = b3[c4 + 0];
      acc[kk][1] = b3[c4 + 1];
      acc[kk][2] = b3[c4 + 2];
      acc[kk][3] = b3[c4 + 3];
    }
    for (int f = 0; f < H2c; ++f) {
      float4 wv = *(const float4*)(W3 + f * H3c + c4);
#pragma unroll
      for (int kk = 0; kk < 8; kk++) {
        float a = h2[kb + kk][f];
        acc[kk][0] += a * wv.x;
        acc[kk][1] += a * wv.y;
        acc[kk][2] += a * wv.z;
        acc[kk][3] += a * wv.w;
      }
    }
    float pm[4] = {-INFINITY, -INFINITY, -INFINITY, -INFINITY};
#pragma unroll
    for (int kk = 0; kk < 8; kk++) {
      if (nl[kb + kk] >= 0) {
        pm[0] = fmaxf(pm[0], fmaxf(acc[kk][0], 0.f));
        pm[1] = fmaxf(pm[1], fmaxf(acc[kk][1], 0.f));
        pm[2] = fmaxf(pm[2], fmaxf(acc[kk][2], 0.f));
        pm[3] = fmaxf(pm[3], fmaxf(acc[kk][3], 0.f));
      }
    }
    float* red = &h1[0][0];  // reuse as [8][128]
    red[(tid >> 5) * H3c + c4 + 0] = pm[0];
    red[(tid >> 5) * H3c + c4 + 1] = pm[1];
    red[(tid >> 5) * H3c + c4 + 2] = pm[2];
    red[(tid >> 5) * H3c + c4 + 3] = pm[3];
    __syncthreads();
    if (tid < H3c) {
      float m = -INFINITY;
#pragma unroll
      for (int r = 0; r < 8; r++) m = fmaxf(m, red[r * H3c + tid]);
      x_out[(size_t)g * H3c + tid] = m;
    }
  }
}

extern "C" void kernel_launch(void* const* d_in, const int* in_sizes, int n_in,
                              void* d_out, int out_size, void* d_ws, size_t ws_size,
                              hipStream_t stream) {
  const float* x = (const float*)d_in[0];
  const float* pos = (const float*)d_in[1];
  // d_in[2] = batch (int32) unused: clouds are equal-size by construction
  const float* W1 = (const float*)d_in[3];
  const float* b1 = (const float*)d_in[4];
  const float* W2 = (const float*)d_in[5];
  const float* b2 = (const float*)d_in[6];
  const float* W3 = (const float*)d_in[7];
  const float* b3 = (const float*)d_in[8];

  float* out = (float*)d_out;
  float* x_out = out;                                    // [B*S, 128]
  float* pos_out = out + (size_t)BB * SS * H3c;          // [B*S, 3]
  float* batch_out = pos_out + (size_t)BB * SS * 3;      // [B*S]

  const size_t y1_bytes = (size_t)BB * NN * H1c * sizeof(float);   // 8 MB
  const size_t nbr_bytes = (size_t)BB * SS * KK * sizeof(int);     // 4 MB
  if (ws_size < y1_bytes + nbr_bytes) return;
  float* y1 = (float*)d_ws;
  int* nbr = (int*)((char*)d_ws + y1_bytes);

  fps_kernel<<<BB, 256, 0, stream>>>(pos, pos_out, batch_out);
  y1_kernel<<<(BB * NN) / 64, 256, 0, stream>>>(x, W1, b1, y1);
  ballq_kernel<<<BB * 64, 256, 0, stream>>>(pos, pos_out, nbr);
  mlp_kernel<<<BB * SS, 256, 0, stream>>>(pos, y1, W1, W2, b2, W3, b3, nbr, pos_out, x_out);
}

// Round 6
// 1899.193 us; speedup vs baseline: 1.4768x; 1.4768x over previous
//
#include <hip/hip_runtime.h>
#include <cstdint>
#include <cstddef>

#define BB 8
#define NN 4096
#define FF 64
#define SS 2048
#define KK 64
#define H1c 64
#define H2c 64
#define H3c 128
#define R2 0.04f
#define CAP 448

typedef unsigned long long ull;
typedef __attribute__((ext_vector_type(2))) float f32x2;
typedef __attribute__((ext_vector_type(4))) float f32x4;
typedef __attribute__((ext_vector_type(8))) short bf16x8;

// ---- packed f32 ops via VOP3P inline asm: exact per-half IEEE, no contraction
__device__ __forceinline__ f32x2 pk_sub(f32x2 a, f32x2 b) {
  f32x2 d;
  asm("v_pk_add_f32 %0, %1, %2 neg_lo:[0,1] neg_hi:[0,1]" : "=v"(d) : "v"(a), "v"(b));
  return d;
}
__device__ __forceinline__ f32x2 pk_mul(f32x2 a, f32x2 b) {
  f32x2 d;
  asm("v_pk_mul_f32 %0, %1, %2" : "=v"(d) : "v"(a), "v"(b));
  return d;
}
__device__ __forceinline__ f32x2 pk_add(f32x2 a, f32x2 b) {
  f32x2 d;
  asm("v_pk_add_f32 %0, %1, %2" : "=v"(d) : "v"(a), "v"(b));
  return d;
}

// Exact (numpy-order, non-fma) squared distance: (dx*dx + dy*dy) + dz*dz
__device__ __forceinline__ float d2_exact(float ax, float ay, float az,
                                          float bx, float by, float bz) {
  float dx = __fsub_rn(ax, bx);
  float dy = __fsub_rn(ay, by);
  float dz = __fsub_rn(az, bz);
  return __fadd_rn(__fadd_rn(__fmul_rn(dx, dx), __fmul_rn(dy, dy)), __fmul_rn(dz, dz));
}

// round-to-nearest-even float -> bf16 bits
__device__ __forceinline__ unsigned short f2bf(float f) {
  unsigned u = __float_as_uint(f);
  return (unsigned short)((u + 0x7fffu + ((u >> 16) & 1u)) >> 16);
}

#define WAVE_MAX_DPP(v)                                                        \
  do {                                                                         \
    v = max(v, __builtin_amdgcn_update_dpp(0, v, 0x111, 0xf, 0xf, true));      \
    v = max(v, __builtin_amdgcn_update_dpp(0, v, 0x112, 0xf, 0xf, true));      \
    v = max(v, __builtin_amdgcn_update_dpp(0, v, 0x114, 0xf, 0xf, true));      \
    v = max(v, __builtin_amdgcn_update_dpp(0, v, 0x118, 0xf, 0xf, true));      \
    v = max(v, __builtin_amdgcn_update_dpp(0, v, 0x142, 0xf, 0xf, true));      \
    v = max(v, __builtin_amdgcn_update_dpp(0, v, 0x143, 0xf, 0xf, true));      \
  } while (0)

// ---------------- Kernel 1: FPS — R1 structure + packed-f32 d2 --------------
// 256 threads, 16 contiguous points/thread (lane order == index order).
// Per step: pk d2+dmin update, u64 key tree (value<<32 | ~idx -> numpy
// first-max tie-break), DPP wave value-max, ballot+ctz -> winner lane's key,
// single barrier, 4-key tournament, broadcast LDS gather of next centroid.
__global__ __launch_bounds__(256) void fps_kernel(const float* __restrict__ pos,
                                                  float* __restrict__ pos_out,
                                                  float* __restrict__ batch_out) {
  __shared__ float plds[NN * 3];
  __shared__ ull skey[2][4];
  const int b = blockIdx.x;
  const int tid = threadIdx.x;
  const float4* src = (const float4*)(pos + (size_t)b * NN * 3);
  float4* dstl = (float4*)plds;
#pragma unroll
  for (int k = 0; k < 12; ++k) dstl[tid + k * 256] = src[tid + k * 256];
  __syncthreads();

  f32x2 px[8], py[8], pz[8], dm[8];
#pragma unroll
  for (int jx = 0; jx < 8; ++jx) {
    int p = tid * 16 + 2 * jx;
    px[jx] = (f32x2){plds[p * 3 + 0], plds[p * 3 + 3]};
    py[jx] = (f32x2){plds[p * 3 + 1], plds[p * 3 + 4]};
    pz[jx] = (f32x2){plds[p * 3 + 2], plds[p * 3 + 5]};
    dm[jx] = (f32x2){INFINITY, INFINITY};
  }
  const int lane = tid & 63, wv = tid >> 6;
  float cx = plds[0], cy = plds[1], cz = plds[2];

  for (int s = 0; s < SS; ++s) {
    if (tid == 0) {
      int o = b * SS + s;
      pos_out[o * 3 + 0] = cx;
      pos_out[o * 3 + 1] = cy;
      pos_out[o * 3 + 2] = cz;
    }
    const f32x2 cvx = (f32x2){cx, cx}, cvy = (f32x2){cy, cy}, cvz = (f32x2){cz, cz};
    ull kk[16];
#pragma unroll
    for (int jx = 0; jx < 8; ++jx) {
      f32x2 dx = pk_sub(px[jx], cvx);
      f32x2 dy = pk_sub(py[jx], cvy);
      f32x2 dz = pk_sub(pz[jx], cvz);
      f32x2 d = pk_add(pk_add(pk_mul(dx, dx), pk_mul(dy, dy)), pk_mul(dz, dz));
      dm[jx].x = fminf(dm[jx].x, d.x);
      dm[jx].y = fminf(dm[jx].y, d.y);
      kk[2 * jx] =
          ((ull)__float_as_uint(dm[jx].x) << 32) | (unsigned)(~(tid * 16 + 2 * jx));
      kk[2 * jx + 1] =
          ((ull)__float_as_uint(dm[jx].y) << 32) | (unsigned)(~(tid * 16 + 2 * jx + 1));
    }
#pragma unroll
    for (int st = 1; st < 16; st <<= 1)
#pragma unroll
      for (int i = 0; i < 16; i += 2 * st)
        if (kk[i + st] > kk[i]) kk[i] = kk[i + st];
    const ull best = kk[0];

    const int hi = (int)(unsigned)(best >> 32);
    int v = hi;
    WAVE_MAX_DPP(v);
    const int wmax = __builtin_amdgcn_readlane(v, 63);
    // lowest lane holding the max value owns the lowest point index
    const ull bal = __ballot(hi == wmax);
    const int wl = (int)__builtin_ctzll(bal);
    const unsigned klo =
        (unsigned)__builtin_amdgcn_readlane((int)(unsigned)best, wl);
    const int buf = s & 1;
    if (lane == 0) skey[buf][wv] = ((ull)(unsigned)wmax << 32) | klo;
    __syncthreads();

    const ull k0 = skey[buf][0], k1 = skey[buf][1];
    const ull k2 = skey[buf][2], k3 = skey[buf][3];
    ull ka = k0 > k1 ? k0 : k1;
    const ull kb2 = k2 > k3 ? k2 : k3;
    if (kb2 > ka) ka = kb2;
    const int cur = (int)(~(unsigned)(ka & 0xffffffffu));
    cx = plds[cur * 3 + 0];
    cy = plds[cur * 3 + 1];
    cz = plds[cur * 3 + 2];
  }
  for (int i = tid; i < SS; i += 256) batch_out[b * SS + i] = (float)b;
}

// ---------------- Kernel 2: y1 = x @ W1[0:64,:] + b1 -> bf16 ----------------
__global__ __launch_bounds__(256) void y1_kernel(const float* __restrict__ x,
                                                 const float* __restrict__ W1,
                                                 const float* __restrict__ b1,
                                                 unsigned short* __restrict__ y1b) {
  __shared__ float xs[64][65];
  const int tid = threadIdx.x;
  const int r0 = blockIdx.x * 64;
  const float4* src = (const float4*)(x + (size_t)r0 * FF);
#pragma unroll
  for (int q = 0; q < 4; q++) {
    int p = tid + q * 256;
    float4 v = src[p];
    int row = (p * 4) >> 6, col = (p * 4) & 63;
    xs[row][col + 0] = v.x;
    xs[row][col + 1] = v.y;
    xs[row][col + 2] = v.z;
    xs[row][col + 3] = v.w;
  }
  __syncthreads();
  const int c4 = (tid & 15) * 4, kb = (tid >> 4) * 4;
  float acc[4][4];
#pragma unroll
  for (int kk = 0; kk < 4; kk++) {
    acc[kk][0] = b1[c4 + 0];
    acc[kk][1] = b1[c4 + 1];
    acc[kk][2] = b1[c4 + 2];
    acc[kk][3] = b1[c4 + 3];
  }
  for (int f = 0; f < FF; ++f) {
    float4 w = *(const float4*)(W1 + f * H1c + c4);
#pragma unroll
    for (int kk = 0; kk < 4; kk++) {
      float a = xs[kb + kk][f];
      acc[kk][0] += a * w.x;
      acc[kk][1] += a * w.y;
      acc[kk][2] += a * w.z;
      acc[kk][3] += a * w.w;
    }
  }
#pragma unroll
  for (int kk = 0; kk < 4; kk++) {
    ushort4 o;
    o.x = f2bf(acc[kk][0]);
    o.y = f2bf(acc[kk][1]);
    o.z = f2bf(acc[kk][2]);
    o.w = f2bf(acc[kk][3]);
    *(ushort4*)(y1b + (size_t)(r0 + kb + kk) * H1c + c4) = o;
  }
}

// ---------------- Kernel 2b: pack W2/W3 into bf16 MFMA B-fragment order -----
// B[k][n] frag: lane l holds k = s*32 + 8*(l>>4)+j, n = c*16 + (l&15).
// Layout: wpack[((c*2+s)*64 + l)*8 + j]
__global__ __launch_bounds__(256) void prep_kernel(const float* __restrict__ W2,
                                                   const float* __restrict__ W3,
                                                   unsigned short* __restrict__ w2p,
                                                   unsigned short* __restrict__ w3p) {
  const int tid = threadIdx.x;
  for (int e = tid; e < 4096; e += 256) {
    int j = e & 7, l = (e >> 3) & 63, s = (e >> 9) & 1, c = e >> 10;
    w2p[e] = f2bf(W2[(s * 32 + 8 * (l >> 4) + j) * H2c + c * 16 + (l & 15)]);
  }
  for (int e = tid; e < 8192; e += 256) {
    int j = e & 7, l = (e >> 3) & 63, s = (e >> 9) & 1, c = e >> 10;
    w3p[e] = f2bf(W3[(s * 32 + 8 * (l >> 4) + j) * H3c + c * 16 + (l & 15)]);
  }
}

// ---------------- Kernel 3: radius ball query, K nearest inside R -----------
__global__ __launch_bounds__(256) void ballq_kernel(const float* __restrict__ pos,
                                                    const float* __restrict__ pos_out,
                                                    int* __restrict__ nbr) {
  __shared__ float plds[NN * 3];
  __shared__ float d2c[4][CAP];
  __shared__ int idxc[4][CAP];
  const int tid = threadIdx.x;
  const int b = blockIdx.x >> 6;
  const int chunk = blockIdx.x & 63;
  const float4* src = (const float4*)(pos + (size_t)b * NN * 3);
  float4* dstl = (float4*)plds;
#pragma unroll
  for (int k = 0; k < 12; k++) dstl[tid + k * 256] = src[tid + k * 256];
  __syncthreads();

  const int w = tid >> 6, lane = tid & 63;
  for (int t8 = 0; t8 < 8; ++t8) {
    const int s = chunk * 32 + w * 8 + t8;
    const int g = b * SS + s;
    const float cx = pos_out[g * 3 + 0], cy = pos_out[g * 3 + 1], cz = pos_out[g * 3 + 2];
    int cnt = 0;
    for (int t = 0; t < 64; ++t) {
      int j = t * 64 + lane;
      float d2 = d2_exact(plds[j * 3 + 0], plds[j * 3 + 1], plds[j * 3 + 2], cx, cy, cz);
      bool pred = (d2 <= R2);
      unsigned long long mask = __ballot(pred);
      if (pred) {
        int p = cnt + __popcll(mask & ((1ull << lane) - 1ull));
        if (p < CAP) { d2c[w][p] = d2; idxc[w][p] = j; }
      }
      cnt += (int)__popcll(mask);
    }
    int M = cnt < CAP ? cnt : CAP;
    __syncthreads();

    if (M <= 64) {
      int v = (lane < M) ? (b * NN + idxc[w][lane]) : -1;
      nbr[(size_t)g * KK + lane] = v;
    } else {
      float ed[7];
      int ei[7];
#pragma unroll
      for (int q = 0; q < 7; q++) {
        int p = lane + q * 64;
        if (p < M) { ed[q] = d2c[w][p]; ei[q] = idxc[w][p]; }
        else { ed[q] = 0.f; ei[q] = -1; }
      }
      for (int it = 0; it < KK; ++it) {
        unsigned long long key = ~0ull;
#pragma unroll
        for (int q = 0; q < 7; q++) {
          if (ei[q] >= 0) {
            unsigned long long k2 =
                ((unsigned long long)__float_as_uint(ed[q]) << 32) | (unsigned)ei[q];
            if (k2 < key) key = k2;
          }
        }
#pragma unroll
        for (int off = 32; off; off >>= 1) {
          unsigned long long ok = __shfl_xor(key, off);
          if (ok < key) key = ok;
        }
        int widx = (int)(key & 0xffffffffull);
        if (lane == it) nbr[(size_t)g * KK + it] = b * NN + widx;
#pragma unroll
        for (int q = 0; q < 7; q++) {
          if (ei[q] == widx) ei[q] = -1;
        }
      }
    }
    __syncthreads();
  }
}

// ---------------- Kernel 4: MFMA MLP (bf16 in, fp32 accum) + max aggr -------
// One block per centroid; 4 waves; wave w owns neighbor rows 16w..16w+15.
// A-frag (16x32): lane l holds A[l&15][8*(l>>4)+j]; B-frag: B[8*(l>>4)+j][l&15];
// C/D: lane l holds D[4*(l>>4)+t][l&15]  (verified layout, m89/m91).
__global__ __launch_bounds__(256) void mlp_kernel(
    const float* __restrict__ pos, const unsigned short* __restrict__ y1b,
    const float* __restrict__ W1, const float* __restrict__ b2,
    const float* __restrict__ b3, const unsigned short* __restrict__ w2p,
    const unsigned short* __restrict__ w3p, const int* __restrict__ nbr,
    const float* __restrict__ pos_out, float* __restrict__ x_out) {
  __shared__ __align__(16) unsigned short lw2[4096];   // 8 KB
  __shared__ __align__(16) unsigned short lw3[8192];   // 16 KB
  __shared__ float w1r[3][64];
  __shared__ int nl[64];
  __shared__ float red[4][128];
  __shared__ __align__(16) unsigned short h2t[4][16][88];  // pad->176B rows
  const int g = blockIdx.x;
  const int tid = threadIdx.x;

  {
    const uint4* s2 = (const uint4*)w2p;
    uint4* d2v = (uint4*)lw2;
    for (int i = tid; i < 512; i += 256) d2v[i] = s2[i];
    const uint4* s3 = (const uint4*)w3p;
    uint4* d3v = (uint4*)lw3;
    for (int i = tid; i < 1024; i += 256) d3v[i] = s3[i];
    if (tid < 192) w1r[tid / 64][tid % 64] = W1[(64 + tid / 64) * H1c + (tid % 64)];
    if (tid < 64) nl[tid] = nbr[(size_t)g * KK + tid];
  }
  const float cx = pos_out[g * 3 + 0], cy = pos_out[g * 3 + 1], cz = pos_out[g * 3 + 2];
  __syncthreads();

  const int lane = tid & 63, wv = tid >> 6;
  const int lrow = lane & 15, g16 = lane >> 4;
  const int r = wv * 16 + lrow;
  const int j = nl[r];

  // ---- layer 1 directly into A-fragments (in-register) ----
  bf16x8 a0 = (bf16x8)0, a1 = (bf16x8)0;
  if (j >= 0) {
    const float rx = pos[j * 3 + 0] - cx;
    const float ry = pos[j * 3 + 1] - cy;
    const float rz = pos[j * 3 + 2] - cz;
    const unsigned short* yr = y1b + (size_t)j * H1c;
    uint4 vlo = *(const uint4*)(yr + 8 * g16);
    uint4 vhi = *(const uint4*)(yr + 32 + 8 * g16);
    const unsigned* plo = (const unsigned*)&vlo;
    const unsigned* phi = (const unsigned*)&vhi;
#pragma unroll
    for (int q = 0; q < 4; ++q) {
      unsigned u = plo[q];
      int k0 = 8 * g16 + 2 * q;
      float e0 = __uint_as_float(u << 16) + rx * w1r[0][k0] + ry * w1r[1][k0] +
                 rz * w1r[2][k0];
      float e1 = __uint_as_float(u & 0xffff0000u) + rx * w1r[0][k0 + 1] +
                 ry * w1r[1][k0 + 1] + rz * w1r[2][k0 + 1];
      a0[2 * q] = (short)f2bf(fmaxf(e0, 0.f));
      a0[2 * q + 1] = (short)f2bf(fmaxf(e1, 0.f));
      unsigned u2 = phi[q];
      int k1 = 32 + k0;
      float f0 = __uint_as_float(u2 << 16) + rx * w1r[0][k1] + ry * w1r[1][k1] +
                 rz * w1r[2][k1];
      float f1 = __uint_as_float(u2 & 0xffff0000u) + rx * w1r[0][k1 + 1] +
                 ry * w1r[1][k1 + 1] + rz * w1r[2][k1 + 1];
      a1[2 * q] = (short)f2bf(fmaxf(f0, 0.f));
      a1[2 * q + 1] = (short)f2bf(fmaxf(f1, 0.f));
    }
  }

  // ---- layer 2: D2(16x64) = h1(16x64) @ W2, relu -> LDS transpose tile ----
  const bf16x8* w2f = (const bf16x8*)lw2;
  const bf16x8* w3f = (const bf16x8*)lw3;
#pragma unroll
  for (int c = 0; c < 4; ++c) {
    float bb = b2[c * 16 + lrow];
    f32x4 acc = {bb, bb, bb, bb};
    acc = __builtin_amdgcn_mfma_f32_16x16x32_bf16(a0, w2f[(c * 2 + 0) * 64 + lane], acc, 0, 0, 0);
    acc = __builtin_amdgcn_mfma_f32_16x16x32_bf16(a1, w2f[(c * 2 + 1) * 64 + lane], acc, 0, 0, 0);
#pragma unroll
    for (int t = 0; t < 4; ++t)
      h2t[wv][4 * g16 + t][c * 16 + lrow] = f2bf(fmaxf(acc[t], 0.f));
  }

  // ---- within-wave transpose read: h2 A-frags ----
  bf16x8 a20 = *(const bf16x8*)&h2t[wv][lrow][8 * g16];
  bf16x8 a21 = *(const bf16x8*)&h2t[wv][lrow][32 + 8 * g16];

  // ---- layer 3 + masked max over this wave's 16 rows ----
  float vmax[8];
#pragma unroll
  for (int c = 0; c < 8; ++c) {
    float bb = b3[c * 16 + lrow];
    f32x4 acc = {bb, bb, bb, bb};
    acc = __builtin_amdgcn_mfma_f32_16x16x32_bf16(a20, w3f[(c * 2 + 0) * 64 + lane], acc, 0, 0, 0);
    acc = __builtin_amdgcn_mfma_f32_16x16x32_bf16(a21, w3f[(c * 2 + 1) * 64 + lane], acc, 0, 0, 0);
    float m = -INFINITY;
#pragma unroll
    for (int t = 0; t < 4; ++t) {
      int rg = wv * 16 + 4 * g16 + t;
      float val = (nl[rg] >= 0) ? fmaxf(acc[t], 0.f) : -INFINITY;
      m = fmaxf(m, val);
    }
    m = fmaxf(m, __shfl_xor(m, 16));
    m = fmaxf(m, __shfl_xor(m, 32));
    vmax[c] = m;
  }
  if (g16 == 0) {
#pragma unroll
    for (int c = 0; c < 8; ++c) red[wv][c * 16 + lrow] = vmax[c];
  }
  __syncthreads();
  if (tid < H3c) {
    float m = fmaxf(fmaxf(red[0][tid], red[1][tid]), fmaxf(red[2][tid], red[3][tid]));
    x_out[(size_t)g * H3c + tid] = m;
  }
}

extern "C" void kernel_launch(void* const* d_in, const int* in_sizes, int n_in,
                              void* d_out, int out_size, void* d_ws, size_t ws_size,
                              hipStream_t stream) {
  const float* x = (const float*)d_in[0];
  const float* pos = (const float*)d_in[1];
  // d_in[2] = batch (int32) unused: clouds are equal-size by construction
  const float* W1 = (const float*)d_in[3];
  const float* b1 = (const float*)d_in[4];
  const float* W2 = (const float*)d_in[5];
  const float* b2 = (const float*)d_in[6];
  const float* W3 = (const float*)d_in[7];
  const float* b3 = (const float*)d_in[8];

  float* out = (float*)d_out;
  float* x_out = out;                                    // [B*S, 128]
  float* pos_out = out + (size_t)BB * SS * H3c;          // [B*S, 3]
  float* batch_out = pos_out + (size_t)BB * SS * 3;      // [B*S]

  const size_t y1_bytes = (size_t)BB * NN * H1c * sizeof(unsigned short);  // 4 MB
  const size_t nbr_bytes = (size_t)BB * SS * KK * sizeof(int);             // 4 MB
  const size_t w2p_bytes = 4096 * sizeof(unsigned short);
  const size_t w3p_bytes = 8192 * sizeof(unsigned short);
  if (ws_size < y1_bytes + nbr_bytes + w2p_bytes + w3p_bytes) return;
  unsigned short* y1b = (unsigned short*)d_ws;
  int* nbr = (int*)((char*)d_ws + y1_bytes);
  unsigned short* w2p = (unsigned short*)((char*)d_ws + y1_bytes + nbr_bytes);
  unsigned short* w3p = w2p + 4096;

  fps_kernel<<<BB, 256, 0, stream>>>(pos, pos_out, batch_out);
  y1_kernel<<<(BB * NN) / 64, 256, 0, stream>>>(x, W1, b1, y1b);
  prep_kernel<<<1, 256, 0, stream>>>(W2, W3, w2p, w3p);
  ballq_kernel<<<BB * 64, 256, 0, stream>>>(pos, pos_out, nbr);
  mlp_kernel<<<BB * SS, 256, 0, stream>>>(pos, y1b, W1, b2, b3, w2p, w3p, nbr,
                                          pos_out, x_out);
}